// Round 8
// baseline (1044.229 us; speedup 1.0000x reference)
//
#include <hip/hip_runtime.h>
#include <hip/hip_bf16.h>
#include <stdint.h>

typedef unsigned short u16;
typedef __attribute__((ext_vector_type(4))) float f32x4;
typedef __attribute__((ext_vector_type(8))) __bf16 bf16x8;

#define K_DIM 4096

// ---------- helpers ----------
__device__ __forceinline__ u16 f2bf_rne(float f) {
  union { float f; uint32_t u; } v; v.f = f;
  uint32_t u = v.u;
  return (u16)((u + 0x7fffu + ((u >> 16) & 1u)) >> 16);
}

__device__ __forceinline__ void gld_lds16(const u16* g, u16* l) {
  __builtin_amdgcn_global_load_lds((const __attribute__((address_space(1))) void*)g,
                                   (__attribute__((address_space(3))) void*)l,
                                   16, 0, 0);
}

// ---------- kernel 0: x (fp32) -> Xb (bf16) ----------
__global__ __launch_bounds__(256) void k_cvt_x(const float* __restrict__ x, u16* __restrict__ xb, int n4) {
  const int stride = gridDim.x * 256;
  for (int i = blockIdx.x * 256 + threadIdx.x; i < n4; i += stride) {
    f32x4 a = ((const f32x4*)x)[i];
    uint2 o;
    o.x = (uint32_t)f2bf_rne(a[0]) | ((uint32_t)f2bf_rne(a[1]) << 16);
    o.y = (uint32_t)f2bf_rne(a[2]) | ((uint32_t)f2bf_rne(a[3]) << 16);
    ((uint2*)xb)[i] = o;
  }
}

// ---------- kernel 1: T1[64][4096] = core0(64x64) @ core1(64x4096) ----------
__global__ __launch_bounds__(256) void k_t1(const float* __restrict__ c0, const float* __restrict__ c1,
                                            float* __restrict__ T1) {
  const int col = blockIdx.x * 256 + threadIdx.x;
  const int row = blockIdx.y;
  float acc = 0.f;
#pragma unroll 16
  for (int r = 0; r < 64; ++r) acc += c0[row * 64 + r] * c1[(size_t)r * 4096 + col];
  T1[(size_t)row * 4096 + col] = acc;
}

// ---------- kernel 2: T2[4096][4096] = T1r(4096x64) @ core2(64x4096) ----------
__global__ __launch_bounds__(256) void k_t2(const float* __restrict__ T1, const float* __restrict__ c2,
                                            float* __restrict__ T2) {
  __shared__ float t1s[16][64];
  const int tid = threadIdx.x;
  const int rowbase = blockIdx.y * 16;
  for (int idx = tid; idx < 1024; idx += 256)
    t1s[idx >> 6][idx & 63] = T1[(size_t)(rowbase + (idx >> 6)) * 64 + (idx & 63)];
  __syncthreads();
  const int col = blockIdx.x * 256 + tid;
  float acc[16];
#pragma unroll
  for (int j = 0; j < 16; ++j) acc[j] = 0.f;
  for (int r = 0; r < 64; ++r) {
    float b = c2[(size_t)r * 4096 + col];
#pragma unroll
    for (int j = 0; j < 16; ++j) acc[j] += t1s[j][r] * b;
  }
#pragma unroll
  for (int j = 0; j < 16; ++j) T2[(size_t)(rowbase + j) * 4096 + col] = acc[j];
}

// ---------- kernel 3: per row12, M = T2row(64x64) @ c3(64x64), transposed-c3 vector reads ----------
__global__ __launch_bounds__(256) void k_w(const float* __restrict__ T2, const float* __restrict__ c3,
                                           u16* __restrict__ Wb) {
  __shared__ float t2p[64 * 65];   // [io3][r3], pad 65: bank=(row+r3)%32 -> 2-way max (free)
  __shared__ float c3t[64 * 64];   // [r3][o4*8 + i4]  (transposed inner dims)
  const int tid = threadIdx.x;
  const int row12 = blockIdx.x;
  for (int idx = tid; idx < 4096; idx += 256) {
    t2p[(idx >> 6) * 65 + (idx & 63)] = T2[(size_t)row12 * 4096 + idx];
    const int r3 = idx >> 6, orow = idx & 63;  // orow = i4*8 + o4
    c3t[r3 * 64 + ((orow & 7) << 3) + (orow >> 3)] = c3[idx];
  }
  __syncthreads();
  const int orow = tid >> 2;        // o3*8+o4
  const int o3 = orow >> 3, o4 = orow & 7;
  const int ib16 = (tid & 3) * 16;
  const int rowA = ((ib16 >> 3)) * 8 + o3;
  const int rowB = ((ib16 >> 3) + 1) * 8 + o3;
  float acc[16];
#pragma unroll
  for (int c = 0; c < 16; ++c) acc[c] = 0.f;
  for (int r3 = 0; r3 < 64; ++r3) {
    const float ta = t2p[rowA * 65 + r3];
    const float tb = t2p[rowB * 65 + r3];
    const float* cv = &c3t[r3 * 64 + o4 * 8];
    f32x4 c0v = *(const f32x4*)cv;
    f32x4 c1v = *(const f32x4*)(cv + 4);
#pragma unroll
    for (int j = 0; j < 4; ++j) {
      acc[j]      += ta * c0v[j];
      acc[4 + j]  += ta * c1v[j];
      acc[8 + j]  += tb * c0v[j];
      acc[12 + j] += tb * c1v[j];
    }
  }
  const int i1o1 = row12 >> 6, i2o2 = row12 & 63;
  const int obase = ((i1o1 & 7) << 9) | ((i2o2 & 7) << 6);
  const int ibase = ((i1o1 >> 3) << 9) | ((i2o2 >> 3) << 6);
  uint32_t pk[8];
#pragma unroll
  for (int c = 0; c < 8; ++c)
    pk[c] = (uint32_t)f2bf_rne(acc[2 * c]) | ((uint32_t)f2bf_rne(acc[2 * c + 1]) << 16);
  uint4* dst = (uint4*)&Wb[(size_t)(obase + orow) * 4096 + ibase + ib16];
  dst[0] = make_uint4(pk[0], pk[1], pk[2], pk[3]);
  dst[1] = make_uint4(pk[4], pk[5], pk[6], pk[7]);
}

// ---------- kernel 4: out(16384x4096) = Xb @ Wb^T + bias ----------
// 256x256 tile, 8 waves (2Mx4N), BK=64, 2-deep LDS dbuf, 4 phases/K-tile.
// DEEP pipeline: tile T stages tile T+2 into buf[P] (the buffer T itself reads),
// issuing each set right after its region's last read: ph1: A0+B0, ph2: B1, ph3: A1.
// -> 6 phases of slack per set. Counted waits (never 0 in steady state):
//   end-ph0 vmcnt(10) retires B1(T); end-ph1 vmcnt(12) retires A1(T);
//   end-ph3 vmcnt(12) retires A0,B0(T+1). Invariant entering a tile: 12 outstanding.
// XOR-swizzled LDS: write via pre-swizzled global source, read chunk ^= row&7.
__global__ __launch_bounds__(512, 2) void k_gemm(const u16* __restrict__ Xb, const u16* __restrict__ Wb,
                                                 const float* __restrict__ bias, float* __restrict__ out) {
  __shared__ alignas(16) u16 Abuf[2][256 * 64];  // 64 KiB
  __shared__ alignas(16) u16 Bbuf[2][256 * 64];  // 64 KiB
  const int tid = threadIdx.x;
  const int wid = tid >> 6, l = tid & 63;
  const int bm = blockIdx.x;  // 0..63
  const int bn = blockIdx.y;  // 0..15
  const int wm = wid >> 2, wn = wid & 3;

  // --- staging (write): LDS linear, global chunk pre-swizzled: chunk = (l&7)^((l>>3)&7) ---
  const int sch = (l & 7) ^ ((l >> 3) & 7);
  const int arow_g = 8 * wid + (l >> 3);                         // A row within 64-row group
  const int brow_g = (wid >> 2) * 64 + 8 * (wid & 3) + (l >> 3); // B row within stripe pattern
  const u16* AgBase = Xb + (size_t)(bm * 256) * K_DIM + sch * 8;
  const u16* BgBase = Wb + (size_t)(bn * 256) * K_DIM + sch * 8;
  const int aldsw = (8 * wid) * 64;                              // wave-uniform LDS elem base
  const int bldsw = ((wid >> 2) * 64 + 8 * (wid & 3)) * 64;

  // --- read: row&7 == l&7 (all row bases are multiples of 16) -> lane-constant swizzle ---
  const int kc0 = (((l >> 4)) ^ (l & 7)) * 8;       // k-half 0 chunk, swizzled, in elems
  const int kc1 = ((4 + (l >> 4)) ^ (l & 7)) * 8;   // k-half 1
  const int aoff = (wm * 128 + (l & 15)) * 64;
  const int boff = (wn * 64 + (l & 15)) * 64;

  f32x4 acc[8][4];
#pragma unroll
  for (int m = 0; m < 8; ++m)
#pragma unroll
    for (int n = 0; n < 4; ++n) acc[m][n] = (f32x4){0.f, 0.f, 0.f, 0.f};

  bf16x8 a[4][2], b0[2][2], b1[2][2];

#define STAGE_A(T, S, PB) do { const size_t ko_ = (size_t)(T) * 64;                                  \
    gld_lds16(AgBase + (size_t)((S) * 64 + arow_g) * K_DIM + ko_,        &Abuf[PB][(S) * 4096 + aldsw]);        \
    gld_lds16(AgBase + (size_t)(128 + (S) * 64 + arow_g) * K_DIM + ko_,  &Abuf[PB][8192 + (S) * 4096 + aldsw]); \
  } while (0)
#define STAGE_B(T, S, PB) do { const size_t ko_ = (size_t)(T) * 64;                                  \
    gld_lds16(BgBase + (size_t)((S) * 32 + brow_g) * K_DIM + ko_,        &Bbuf[PB][(S) * 2048 + bldsw]);        \
    gld_lds16(BgBase + (size_t)(128 + (S) * 32 + brow_g) * K_DIM + ko_,  &Bbuf[PB][8192 + (S) * 2048 + bldsw]); \
  } while (0)

#define LDA(P, MH) do { _Pragma("unroll") for (int mt = 0; mt < 4; ++mt) {       \
    a[mt][0] = *(const bf16x8*)&Abuf[P][aoff + (MH) * 4096 + mt * 1024 + kc0];   \
    a[mt][1] = *(const bf16x8*)&Abuf[P][aoff + (MH) * 4096 + mt * 1024 + kc1]; } } while (0)
#define LDB(BV, P, NH) do { _Pragma("unroll") for (int nt = 0; nt < 2; ++nt) {   \
    BV[nt][0] = *(const bf16x8*)&Bbuf[P][boff + (NH) * 2048 + nt * 1024 + kc0];  \
    BV[nt][1] = *(const bf16x8*)&Bbuf[P][boff + (NH) * 2048 + nt * 1024 + kc1]; } } while (0)

#define MM(MB, NB, BV) do { __builtin_amdgcn_s_setprio(1);                                            \
    _Pragma("unroll") for (int mt = 0; mt < 4; ++mt)                                                  \
    _Pragma("unroll") for (int nt = 0; nt < 2; ++nt) {                                                \
      acc[(MB)+mt][(NB)+nt] = __builtin_amdgcn_mfma_f32_16x16x32_bf16(a[mt][0], BV[nt][0], acc[(MB)+mt][(NB)+nt], 0, 0, 0); \
      acc[(MB)+mt][(NB)+nt] = __builtin_amdgcn_mfma_f32_16x16x32_bf16(a[mt][1], BV[nt][1], acc[(MB)+mt][(NB)+nt], 0, 0, 0); } \
    __builtin_amdgcn_s_setprio(0); } while (0)

#define FENCE asm volatile("" ::: "memory")
#define BAR do { FENCE; __builtin_amdgcn_s_barrier(); FENCE; } while (0)
#define VMW(N) asm volatile("s_waitcnt vmcnt(" #N ")" ::: "memory")
#define LGKM do { asm volatile("s_waitcnt lgkmcnt(0)" ::: "memory"); \
    __builtin_amdgcn_sched_barrier(0); } while (0)

// Steady-state per-wave ledger (cadence per tile: ph1 +4, ph2 +2, ph3 +2):
// entering tile T: [B1(T):2, A1(T):2, A0B0(T+1):4, B1(T+1):2, A1(T+1):2] = 12.
// ph0 end VMW(10): retires B1(T)   (6-phase slack; read next phase)
// ph1 end VMW(12): retires A1(T)   (6-phase slack)
// ph2 end: no wait
// ph3 end VMW(12): retires A0B0(T+1) (6-phase slack) -> invariant for T+1.
#define TILE(T, P) do {                                                                              \
    LDA(P, 0); LDB(b0, P, 0);                                 BAR; LGKM; MM(0, 0, b0); VMW(10); BAR; \
    LDB(b1, P, 1); STAGE_A((T)+2, 0, P); STAGE_B((T)+2, 0, P); BAR; LGKM; MM(0, 2, b1); VMW(12); BAR; \
    LDA(P, 1); STAGE_B((T)+2, 1, P);                          BAR; LGKM; MM(4, 2, b1);          BAR; \
    STAGE_A((T)+2, 1, P);                                     BAR;       MM(4, 0, b0); VMW(12); BAR; \
  } while (0)

  // prologue: stage tiles 0 and 1 in ledger order; retire A0B0(0); barrier.
  STAGE_A(0, 0, 0); STAGE_B(0, 0, 0); STAGE_B(0, 1, 0); STAGE_A(0, 1, 0);
  STAGE_A(1, 0, 1); STAGE_B(1, 0, 1); STAGE_B(1, 1, 1); STAGE_A(1, 1, 1);
  VMW(12); BAR;

#pragma unroll 1
  for (int t = 0; t < 62; t += 2) {
    TILE(t, 0);      // stages tile t+2 into buf0
    TILE(t + 1, 1);  // stages tile t+3 into buf1
  }

  // tail tile 62 (P=0, no staging): drain 10 -> 8 -> 4
  LDA(0, 0); LDB(b0, 0, 0); BAR; LGKM; MM(0, 0, b0); VMW(10); BAR;
  LDB(b1, 0, 1);            BAR; LGKM; MM(0, 2, b1); VMW(8);  BAR;
  LDA(0, 1);                BAR; LGKM; MM(4, 2, b1);          BAR;
                            BAR;       MM(4, 0, b0); VMW(4);  BAR;
  // tail tile 63 (P=1): drain 2 -> 0
  LDA(1, 0); LDB(b0, 1, 0); BAR; LGKM; MM(0, 0, b0); VMW(2); BAR;
  LDB(b1, 1, 1);            BAR; LGKM; MM(0, 2, b1); VMW(0); BAR;
  LDA(1, 1);                BAR; LGKM; MM(4, 2, b1);         BAR;
                                       MM(4, 0, b0);

  // epilogue: C/D mapping col=lane&15, row=(lane>>4)*4+j
  const int orow_base = bm * 256 + wm * 128 + (l >> 4) * 4;
  const int ocol_base = bn * 256 + wn * 64 + (l & 15);
#pragma unroll
  for (int n = 0; n < 4; ++n) {
    const int oc = ocol_base + n * 16;
    const float bv = bias[oc];
#pragma unroll
    for (int m = 0; m < 8; ++m) {
      const int orb = orow_base + m * 16;
#pragma unroll
      for (int j = 0; j < 4; ++j)
        out[(size_t)(orb + j) * 4096 + oc] = acc[m][n][j] + bv;
    }
  }
#undef STAGE_A
#undef STAGE_B
#undef LDA
#undef LDB
#undef MM
#undef FENCE
#undef BAR
#undef VMW
#undef LGKM
#undef TILE
}

extern "C" void kernel_launch(void* const* d_in, const int* in_sizes, int n_in,
                              void* d_out, int out_size, void* d_ws, size_t ws_size,
                              hipStream_t stream) {
  const float* x    = (const float*)d_in[0];
  const float* c0   = (const float*)d_in[1];
  const float* c1   = (const float*)d_in[2];
  const float* c2   = (const float*)d_in[3];
  const float* c3   = (const float*)d_in[4];
  const float* bias = (const float*)d_in[5];
  float* out = (float*)d_out;

  char* ws = (char*)d_ws;
  float* T1 = (float*)ws;                                          //  1 MiB: 64*4096 f32
  float* T2 = (float*)(ws + (1u << 20));                           // 64 MiB: 4096*4096 f32
  u16*   Wb = (u16*)(ws + (1u << 20) + (64u << 20));               // 32 MiB: 4096*4096 bf16
  u16*   Xb = (u16*)(ws + (1u << 20) + (64u << 20) + (32u << 20)); // 128 MiB: 16384*4096 bf16

  hipLaunchKernelGGL(k_cvt_x, dim3(2048), dim3(256), 0, stream, x, Xb, 16777216);
  hipLaunchKernelGGL(k_t1,    dim3(16, 64), dim3(256), 0, stream, c0, c1, T1);
  hipLaunchKernelGGL(k_t2,    dim3(16, 256), dim3(256), 0, stream, T1, c2, T2);
  hipLaunchKernelGGL(k_w,     dim3(4096), dim3(256), 0, stream, T2, c3, Wb);
  hipLaunchKernelGGL(k_gemm,  dim3(64, 16), dim3(512), 0, stream, Xb, Wb, bias, out);
}